// Round 11
// baseline (38.960 us; speedup 1.0000x reference)
//
#include <hip/hip_runtime.h>

#define RADIUS 5
#define WIN    11
#define WIN2   121
#define KCLS   6
#define HH     128
#define WW     128
#define BB     4
#define NPIX   (HH*WW)
#define TPB    256                  // 4 lanes per pixel, 64 px (half row)
#define NBLK   (BB*HH*2)            // 1024 blocks
#define PXB    64                   // pixels per block
#define LABW   (PXB + 2*RADIUS)     // 74 cols
#define NSITE  (WIN*LABW)           // 814 sites
#define PLSTR  (NSITE*2)            // floats per class-pair plane

__global__ __launch_bounds__(TPB, 4) void ncut_fused(
    const float* __restrict__ labels,
    const float* __restrict__ weights,
    float* __restrict__ part,         // [NBLK][12] slots (device-scope stores)
    unsigned* __restrict__ counter,
    float* __restrict__ out) {
  // label tile: 3 pair-planes of [site][2 classes] -> ds_read_b64 per pair
  __shared__ float shl[3 * PLSTR];    // 4884 floats = 19.5 KB
  __shared__ float shred[4 * 12];
  __shared__ int   lastFlag;

  const int tid = threadIdx.x;
  const int blk = blockIdx.x;
  const int b   = blk >> 8;                 // 256 blocks per image
  const int rem = blk & 255;
  const int y0  = rem >> 1;
  const int x0  = (rem & 1) * PXB;

  // ---- stage zero-padded label tile, class-pair interleaved ----
  const float* labB = labels + (size_t)b * KCLS * NPIX;
  for (int s = tid; s < NSITE; s += TPB) {
    const int tr = s / LABW;
    const int tc = s - tr * LABW;
    const int gy = y0 - RADIUS + tr;
    const int gx = x0 + tc - RADIUS;
    const bool ok = ((unsigned)gy < (unsigned)HH) & ((unsigned)gx < (unsigned)WW);
    const float* lp = labB + (size_t)gy * WW + gx;
#pragma unroll
    for (int p = 0; p < 3; ++p) {
      float2 v = make_float2(0.f, 0.f);
      if (ok) {
        v.x = lp[(size_t)(2 * p) * NPIX];
        v.y = lp[(size_t)(2 * p + 1) * NPIX];
      }
      *reinterpret_cast<float2*>(shl + p * PLSTR + 2 * s) = v;
    }
  }
  __syncthreads();

  // ---- per-thread: pixel px, tap o = 4j + q ----
  const int px = tid >> 2;          // 0..63
  const int q  = tid & 3;           // 0..3
  // per-instruction: 4 q-lanes read 4 CONSECUTIVE dwords (16B run per px)
  const float* wrowq = weights +
      ((size_t)b * NPIX + (size_t)y0 * WW + x0 + px) * WIN2 + q;

  float2 a0 = make_float2(0.f, 0.f);
  float2 a1 = make_float2(0.f, 0.f);
  float2 a2 = make_float2(0.f, 0.f);
  float wsum = 0.f;

#pragma unroll
  for (int j = 0; j < 30; ++j) {
    const int o4 = 4 * j;                 // group base tap (compile-time)
    const int S  = (o4 / WIN) * LABW + (o4 % WIN);
    const int Wn = WIN - (o4 % WIN);      // taps of this group in same row
    const float w = wrowq[o4];            // tap o = 4j + q
    wsum += w;
    int li = px + S + q;
    if (Wn < 4) li += (q >= Wn) ? (LABW - WIN) : 0;  // row-wrap correction
    const float2 v0 = *reinterpret_cast<const float2*>(shl + 0 * PLSTR + 2 * li);
    const float2 v1 = *reinterpret_cast<const float2*>(shl + 1 * PLSTR + 2 * li);
    const float2 v2 = *reinterpret_cast<const float2*>(shl + 2 * PLSTR + 2 * li);
    a0.x += w * v0.x; a0.y += w * v0.y;
    a1.x += w * v1.x; a1.y += w * v1.y;
    a2.x += w * v2.x; a2.y += w * v2.y;
  }
  if (q == 0) {                      // tail tap o = 120
    const float w = wrowq[120];
    const int li = px + 10 * LABW + 10;
    wsum += w;
    const float2 v0 = *reinterpret_cast<const float2*>(shl + 0 * PLSTR + 2 * li);
    const float2 v1 = *reinterpret_cast<const float2*>(shl + 1 * PLSTR + 2 * li);
    const float2 v2 = *reinterpret_cast<const float2*>(shl + 2 * PLSTR + 2 * li);
    a0.x += w * v0.x; a0.y += w * v0.y;
    a1.x += w * v1.x; a1.y += w * v1.y;
    a2.x += w * v2.x; a2.y += w * v2.y;
  }

  // ---- reduce the 4 q-lanes (xor 1,2) ----
#pragma unroll
  for (int off = 1; off <= 2; off <<= 1) {
    wsum += __shfl_xor(wsum, off);
    a0.x += __shfl_xor(a0.x, off); a0.y += __shfl_xor(a0.y, off);
    a1.x += __shfl_xor(a1.x, off); a1.y += __shfl_xor(a1.y, off);
    a2.x += __shfl_xor(a2.x, off); a2.y += __shfl_xor(a2.y, off);
  }

  // ---- num/den per pixel (center site = 5*74 + 5) ----
  const int lc = px + 5 * LABW + 5;
  const float2 c0 = *reinterpret_cast<const float2*>(shl + 0 * PLSTR + 2 * lc);
  const float2 c1 = *reinterpret_cast<const float2*>(shl + 1 * PLSTR + 2 * lc);
  const float2 c2 = *reinterpret_cast<const float2*>(shl + 2 * PLSTR + 2 * lc);
  float nv[KCLS] = {c0.x * a0.x, c0.y * a0.y, c1.x * a1.x,
                    c1.y * a1.y, c2.x * a2.x, c2.y * a2.y};
  float dv[KCLS] = {c0.x * wsum, c0.y * wsum, c1.x * wsum,
                    c1.y * wsum, c2.x * wsum, c2.y * wsum};

  // ---- reduce across the 16 pixels of this wave (lane bits 2..5) ----
#pragma unroll
  for (int off = 4; off <= 32; off <<= 1) {
#pragma unroll
    for (int k = 0; k < KCLS; ++k) {
      nv[k] += __shfl_xor(nv[k], off);
      dv[k] += __shfl_xor(dv[k], off);
    }
  }
  const int wave = tid >> 6;
  if ((tid & 63) == 0) {
#pragma unroll
    for (int k = 0; k < KCLS; ++k) {
      shred[wave * 12 + k]     = nv[k];
      shred[wave * 12 + 6 + k] = dv[k];
    }
  }
  __syncthreads();

  // ---- per-block slot store (distinct addresses -> no contention) ----
  if (tid < 12) {
    float s = 0.f;
#pragma unroll
    for (int w = 0; w < 4; ++w) s += shred[w * 12 + tid];
    // agent-scope store: device-visible, bypasses non-coherent per-XCD L2
    __hip_atomic_store(part + blk * 12 + tid, s,
                       __ATOMIC_RELAXED, __HIP_MEMORY_SCOPE_AGENT);
  }
  // __syncthreads emits s_waitcnt vmcnt(0) first -> stores complete at device
  __syncthreads();
  if (tid == 0) {
    __threadfence();
    unsigned old = atomicAdd(counter, 1u);
    lastFlag = (old == NBLK - 1) ? 1 : 0;
  }
  __syncthreads();
  if (!lastFlag) return;

  // ---- last block: final reduce over part[1024][12] (agent loads) ----
  float* shf = shl;                 // reuse tile LDS: [8 segs][48]
  const int seg = tid >> 5;         // 0..7
  const int bk  = tid & 31;         // active < 24
  if (bk < 24) {
    const int fb = bk / KCLS;
    const int fk = bk - fb * KCLS;
    const int r0 = fb * 256 + seg * 32;
    float num = 0.f, den = 0.f;
#pragma unroll 4
    for (int i = 0; i < 32; ++i) {
      const float* p = part + (size_t)(r0 + i) * 12;
      num += __hip_atomic_load(p + fk,     __ATOMIC_RELAXED,
                               __HIP_MEMORY_SCOPE_AGENT);
      den += __hip_atomic_load(p + 6 + fk, __ATOMIC_RELAXED,
                               __HIP_MEMORY_SCOPE_AGENT);
    }
    shf[seg * 48 + bk * 2]     = num;
    shf[seg * 48 + bk * 2 + 1] = den;
  }
  __syncthreads();
  float val = 0.f;
  if (tid < 24) {
    float n = 0.f, d = 0.f;
#pragma unroll
    for (int s = 0; s < 8; ++s) {
      n += shf[s * 48 + tid * 2];
      d += shf[s * 48 + tid * 2 + 1];
    }
    val = fabsf(n / d) * (1.0f / BB);
  }
  if (tid < 64) {
#pragma unroll
    for (int off = 32; off; off >>= 1) val += __shfl_down(val, off);
    if (tid == 0) out[0] = (float)KCLS - val;
  }
}

extern "C" void kernel_launch(void* const* d_in, const int* in_sizes, int n_in,
                              void* d_out, int out_size, void* d_ws, size_t ws_size,
                              hipStream_t stream) {
  const float* labels  = (const float*)d_in[0];
  const float* weights = (const float*)d_in[1];
  float* out = (float*)d_out;
  unsigned* counter = (unsigned*)d_ws;                  // 4 B @ offset 0
  float*    part    = (float*)((char*)d_ws + 256);      // 1024*12 floats

  hipMemsetAsync(d_ws, 0, 256, stream);                 // zero counter
  ncut_fused<<<NBLK, TPB, 0, stream>>>(labels, weights, part, counter, out);
}

// Round 12
// 19.807 us; speedup vs baseline: 1.9670x; 1.9670x over previous
//
#include <hip/hip_runtime.h>

#define RADIUS 5
#define WIN    11
#define WIN2   121
#define KCLS   6
#define HH     128
#define WW     128
#define BB     4
#define NPIX   (HH*WW)
#define TPB    256                  // 4 lanes per pixel, 64 px (half row)
#define NBLK   (BB*HH*2)            // 1024 blocks
#define PXB    64                   // pixels per block
#define LABW   (PXB + 2*RADIUS)     // 74 cols
#define NSITE  (WIN*LABW)           // 814 sites
#define PLSTR  (NSITE*2)            // floats per class-pair plane

__global__ __launch_bounds__(TPB, 4) void ncut_main(
    const float* __restrict__ labels,
    const float* __restrict__ weights,
    float* __restrict__ part) {
  // label tile: 3 pair-planes of [site][2 classes] -> ds_read_b64 per pair
  __shared__ float shl[3 * PLSTR];    // 4884 floats = 19.5 KB
  __shared__ float shred[4 * 12];

  const int tid = threadIdx.x;
  const int blk = blockIdx.x;
  const int b   = blk >> 8;                 // 256 blocks per image
  const int rem = blk & 255;
  const int y0  = rem >> 1;
  const int x0  = (rem & 1) * PXB;

  // ---- stage zero-padded label tile, class-pair interleaved ----
  const float* labB = labels + (size_t)b * KCLS * NPIX;
  for (int s = tid; s < NSITE; s += TPB) {
    const int tr = s / LABW;
    const int tc = s - tr * LABW;
    const int gy = y0 - RADIUS + tr;
    const int gx = x0 + tc - RADIUS;
    const bool ok = ((unsigned)gy < (unsigned)HH) & ((unsigned)gx < (unsigned)WW);
    const float* lp = labB + (size_t)gy * WW + gx;
#pragma unroll
    for (int p = 0; p < 3; ++p) {
      float2 v = make_float2(0.f, 0.f);
      if (ok) {
        v.x = lp[(size_t)(2 * p) * NPIX];
        v.y = lp[(size_t)(2 * p + 1) * NPIX];
      }
      *reinterpret_cast<float2*>(shl + p * PLSTR + 2 * s) = v;
    }
  }
  __syncthreads();

  // ---- per-thread: pixel px, quad set {4g+q} on the ALIGNED quad grid ----
  const int px = tid >> 2;          // 0..63
  const int q  = tid & 3;           // 0..3
  const size_t pxg = (size_t)b * NPIX + (size_t)y0 * WW + x0 + px;
  const int S  = (int)(pxg & 3);    // row-start misalignment (floats)
  // 16B-aligned base: each float4 load fetches one line-quarter exactly once
  const float* wal = weights + pxg * WIN2 - S;
  const int T0 = 4 * q - S;

  float2 a0 = make_float2(0.f, 0.f);
  float2 a1 = make_float2(0.f, 0.f);
  float2 a2 = make_float2(0.f, 0.f);
  float wsum = 0.f;

#pragma unroll
  for (int g = 0; g < 8; ++g) {
    // q==3,g==7 would be quad 31 (possibly OOB, taps all >120): clamp to 30
    const int kq = (g == 7) ? ((q == 3) ? 30 : 28 + q) : 4 * g + q;
    const float4 wv = *reinterpret_cast<const float4*>(wal + 4 * kq);
#pragma unroll
    for (int m = 0; m < 4; ++m) {
      float w = (m == 0) ? wv.x : (m == 1) ? wv.y : (m == 2) ? wv.z : wv.w;
      int   t = 16 * g + m + T0;    // tap index (may be <0 or >120 at edges)
      bool valid = true;
      if (g == 0) valid = (q != 0) | (m >= S);            // t >= 0
      if (g == 7) valid = (q < 2) | ((q == 2) & (m <= S)); // t <= 120; q==3 none
      if (!valid) { w = 0.0f; t = 0; }
      const int r  = (t * 5958) >> 16;    // t/11, exact for 0<=t<=123
      const int li = px + t + 63 * r;     // px + row*74 + col
      const float2 v0 = *reinterpret_cast<const float2*>(shl + 2 * li);
      const float2 v1 = *reinterpret_cast<const float2*>(shl + PLSTR + 2 * li);
      const float2 v2 = *reinterpret_cast<const float2*>(shl + 2 * PLSTR + 2 * li);
      wsum += w;
      a0.x += w * v0.x; a0.y += w * v0.y;
      a1.x += w * v1.x; a1.y += w * v1.y;
      a2.x += w * v2.x; a2.y += w * v2.y;
    }
  }

  // ---- reduce the 4 q-lanes (xor 1,2) ----
#pragma unroll
  for (int off = 1; off <= 2; off <<= 1) {
    wsum += __shfl_xor(wsum, off);
    a0.x += __shfl_xor(a0.x, off); a0.y += __shfl_xor(a0.y, off);
    a1.x += __shfl_xor(a1.x, off); a1.y += __shfl_xor(a1.y, off);
    a2.x += __shfl_xor(a2.x, off); a2.y += __shfl_xor(a2.y, off);
  }

  // ---- num/den per pixel (center site = 5*74 + 5) ----
  const int lc = px + 5 * LABW + 5;
  const float2 c0 = *reinterpret_cast<const float2*>(shl + 2 * lc);
  const float2 c1 = *reinterpret_cast<const float2*>(shl + PLSTR + 2 * lc);
  const float2 c2 = *reinterpret_cast<const float2*>(shl + 2 * PLSTR + 2 * lc);
  float nv[KCLS] = {c0.x * a0.x, c0.y * a0.y, c1.x * a1.x,
                    c1.y * a1.y, c2.x * a2.x, c2.y * a2.y};
  float dv[KCLS] = {c0.x * wsum, c0.y * wsum, c1.x * wsum,
                    c1.y * wsum, c2.x * wsum, c2.y * wsum};

  // ---- reduce across the 16 pixels of this wave (lane bits 2..5) ----
#pragma unroll
  for (int off = 4; off <= 32; off <<= 1) {
#pragma unroll
    for (int k = 0; k < KCLS; ++k) {
      nv[k] += __shfl_xor(nv[k], off);
      dv[k] += __shfl_xor(dv[k], off);
    }
  }
  const int wave = tid >> 6;
  if ((tid & 63) == 0) {
#pragma unroll
    for (int k = 0; k < KCLS; ++k) {
      shred[wave * 12 + k]     = nv[k];
      shred[wave * 12 + 6 + k] = dv[k];
    }
  }
  __syncthreads();
  if (tid < 12) {
    float s = 0.f;
#pragma unroll
    for (int w = 0; w < 4; ++w) s += shred[w * 12 + tid];
    part[blk * 12 + tid] = s;
  }
}

// ---- final: L = num/den per (b,k); out = K - (1/B) * sum |L| ----
// 8 segments x 32 (b,k)-slots, 32 block-partials each, LDS reduce.
__global__ __launch_bounds__(256) void ncut_final(
    const float* __restrict__ part, float* __restrict__ out) {
  __shared__ float shf[8 * 48];
  const int t   = threadIdx.x;
  const int seg = t >> 5;           // 0..7
  const int bk  = t & 31;           // active < 24
  if (bk < 24) {
    const int b = bk / KCLS;
    const int k = bk - b * KCLS;
    const int r0 = b * 256 + seg * 32;
    float num = 0.f, den = 0.f;
#pragma unroll 4
    for (int i = 0; i < 32; ++i) {
      const float* p = part + (size_t)(r0 + i) * 12;
      num += p[k];
      den += p[6 + k];
    }
    shf[seg * 48 + bk * 2]     = num;
    shf[seg * 48 + bk * 2 + 1] = den;
  }
  __syncthreads();
  float val = 0.f;
  if (t < 24) {
    float n = 0.f, d = 0.f;
#pragma unroll
    for (int s = 0; s < 8; ++s) {
      n += shf[s * 48 + t * 2];
      d += shf[s * 48 + t * 2 + 1];
    }
    val = fabsf(n / d) * (1.0f / BB);
  }
  if (t < 64) {
#pragma unroll
    for (int off = 16; off; off >>= 1) val += __shfl_down(val, off);
    if (t == 0) out[0] = (float)KCLS - val;
  }
}

extern "C" void kernel_launch(void* const* d_in, const int* in_sizes, int n_in,
                              void* d_out, int out_size, void* d_ws, size_t ws_size,
                              hipStream_t stream) {
  const float* labels  = (const float*)d_in[0];
  const float* weights = (const float*)d_in[1];
  float* out  = (float*)d_out;
  float* part = (float*)d_ws;      // 1024 blocks * 12 floats = 49152 B

  ncut_main<<<NBLK, TPB, 0, stream>>>(labels, weights, part);
  ncut_final<<<1, 256, 0, stream>>>(part, out);
}